// Round 2
// baseline (983.745 us; speedup 1.0000x reference)
//
#include <hip/hip_runtime.h>
#include <stdint.h>

#define N_TOK 16384
#define DIM   1024
#define NEXP  16
#define HID   4096

typedef unsigned short ushort_t;
typedef __bf16 bf16x8 __attribute__((ext_vector_type(8)));
typedef float  f32x4  __attribute__((ext_vector_type(4)));
typedef ushort_t u16x8 __attribute__((ext_vector_type(8)));

// round-to-nearest-even fp32 -> bf16
__device__ __forceinline__ ushort_t f2bf(float f) {
    union { float f; unsigned int u; } v; v.f = f;
    unsigned int r = v.u + 0x7fffu + ((v.u >> 16) & 1u);
    return (ushort_t)(r >> 16);
}

__device__ __forceinline__ void gl_lds16(const void* g, void* l) {
    __builtin_amdgcn_global_load_lds(
        (const __attribute__((address_space(1))) void*)g,
        (__attribute__((address_space(3))) void*)l, 16, 0, 0);
}

// ---------------- fused prep: W1 transpose+cast (z<16) | router (z>=16) ----------------
// Transpose: [E][D][H] fp32 -> [E][H][D] bf16, 64d x 64h tile per block.
// Router: wave per token; logits -> top2 -> (eidx, probs), emit xbf, out=bias part.
// Fused so the HBM-heavy transpose overlaps the L2/VALU-heavy router.
#define TS 72
__global__ void __launch_bounds__(256) prep_kernel(
    const float* __restrict__ x, const float* __restrict__ Wn,
    const float* __restrict__ bn, const float* __restrict__ b2,
    const float* __restrict__ W1,
    ushort_t* __restrict__ xbf, ushort_t* __restrict__ w1t,
    int2* __restrict__ eidx, float2* __restrict__ probs, float* __restrict__ out) {
    __shared__ ushort_t tileT[64 * TS];
    if (blockIdx.z < NEXP) {
        // ---- transpose tile ----
        const int e  = blockIdx.z;
        const int h0 = blockIdx.x * 64;
        const int d0 = blockIdx.y * 64;
        const int t  = threadIdx.x;
        const int hs = t & 15;   // h-group of 4 floats
        const int dg = t >> 4;   // d-group of 4 rows
        const float* src = W1 + (size_t)e * DIM * HID;
        float4 rows[4];
#pragma unroll
        for (int i = 0; i < 4; ++i)
            rows[i] = *(const float4*)(src + (size_t)(d0 + dg * 4 + i) * HID + h0 + hs * 4);
#pragma unroll
        for (int j = 0; j < 4; ++j) {
            float v0 = (&rows[0].x)[j], v1 = (&rows[1].x)[j];
            float v2 = (&rows[2].x)[j], v3 = (&rows[3].x)[j];
            ushort4 col; col.x = f2bf(v0); col.y = f2bf(v1); col.z = f2bf(v2); col.w = f2bf(v3);
            *(ushort4*)&tileT[(hs * 4 + j) * TS + dg * 4] = col;
        }
        __syncthreads();
        ushort_t* dst = w1t + (size_t)e * HID * DIM;
#pragma unroll
        for (int p = 0; p < 2; ++p) {
            int r = p * 32 + (t >> 3);
            int c = t & 7;
            u16x8 fr = *(const u16x8*)&tileT[r * TS + c * 8];
            *(u16x8*)(dst + (size_t)(h0 + r) * DIM + d0 + c * 8) = fr;
        }
    } else {
        // ---- router ----
        const int tb   = (blockIdx.z - NEXP) * 1024 + blockIdx.y * 64 + blockIdx.x;
        const int wave = threadIdx.x >> 6;
        const int lane = threadIdx.x & 63;
        const int token = tb * 4 + wave;
        const float* xr = x + (size_t)token * DIM;
        float acc[NEXP];
#pragma unroll
        for (int e = 0; e < NEXP; ++e) acc[e] = 0.f;
        ushort_t xl[16];
#pragma unroll
        for (int i = 0; i < 16; ++i) {
            int d = lane + i * 64;
            float xv = xr[d];
            xl[i] = f2bf(xv);
            const float4* wr = (const float4*)(Wn + d * NEXP);
            float4 w0 = wr[0], w1 = wr[1], w2 = wr[2], w3 = wr[3];
            acc[0]  += xv * w0.x; acc[1]  += xv * w0.y; acc[2]  += xv * w0.z; acc[3]  += xv * w0.w;
            acc[4]  += xv * w1.x; acc[5]  += xv * w1.y; acc[6]  += xv * w1.z; acc[7]  += xv * w1.w;
            acc[8]  += xv * w2.x; acc[9]  += xv * w2.y; acc[10] += xv * w2.z; acc[11] += xv * w2.w;
            acc[12] += xv * w3.x; acc[13] += xv * w3.y; acc[14] += xv * w3.z; acc[15] += xv * w3.w;
        }
        ushort_t* xbr = xbf + (size_t)token * DIM;
#pragma unroll
        for (int i = 0; i < 16; ++i) xbr[lane + i * 64] = xl[i];
#pragma unroll
        for (int e = 0; e < NEXP; ++e) {
            float v = acc[e];
#pragma unroll
            for (int off = 32; off > 0; off >>= 1) v += __shfl_xor(v, off, 64);
            acc[e] = v + bn[e];
        }
        if (lane == 0) {
            float m0 = -1e30f; int i0 = 0;
            for (int e = 0; e < NEXP; ++e) if (acc[e] > m0) { m0 = acc[e]; i0 = e; }
            float m1 = -1e30f; int i1 = 0;
            for (int e = 0; e < NEXP; ++e) if (e != i0 && acc[e] > m1) { m1 = acc[e]; i1 = e; }
            float tq = expf(m1 - m0);          // m1 <= m0, safe
            float p0 = 1.f / (1.f + tq);
            float p1 = 1.f - p0;
            eidx[token]  = make_int2(i0, i1);
            probs[token] = make_float2(p0, p1);
            out[token]   = p0 * b2[i0] + p1 * b2[i1];
        }
    }
}

// ---------------- bucket build: hist -> scan -> scatter ----------------
#define NCHUNK 64
#define CHUNK  (N_TOK / NCHUNK)   // 256 tokens per chunk

__global__ void __launch_bounds__(256) hist_kernel(const int2* __restrict__ eidx,
                                                   int* __restrict__ counts) {
    __shared__ int h[NEXP];
    const int t = threadIdx.x;
    if (t < NEXP) h[t] = 0;
    __syncthreads();
    int token = blockIdx.x * CHUNK + t;
    int2 ei = eidx[token];
    atomicAdd(&h[ei.x], 1);
    atomicAdd(&h[ei.y], 1);
    __syncthreads();
    if (t < NEXP) counts[t * NCHUNK + blockIdx.x] = h[t];
}

__global__ void __launch_bounds__(1024) scan_kernel(const int* __restrict__ counts,
                                                    int* __restrict__ offs,
                                                    int* __restrict__ cnt) {
    const int w    = threadIdx.x >> 6;
    const int lane = threadIdx.x & 63;
    int v = counts[w * NCHUNK + lane];
    int orig = v;
#pragma unroll
    for (int off = 1; off < 64; off <<= 1) {
        int up = __shfl_up(v, off, 64);
        if (lane >= off) v += up;
    }
    offs[w * NCHUNK + lane] = v - orig;   // exclusive prefix within expert
    if (lane == 63) cnt[w] = v;
}

__global__ void __launch_bounds__(256) scatter_kernel(
    const int2* __restrict__ eidx, const float2* __restrict__ probs,
    const int* __restrict__ offs, int* __restrict__ tok, float* __restrict__ gate) {
    __shared__ int wcnt[4][NEXP];
    const int t = threadIdx.x;
    const int wv = t >> 6, lane = t & 63;
    const int token = blockIdx.x * CHUNK + t;
    int2  ei = eidx[token];
    float2 pr = probs[token];
    unsigned long long lmask = (1ull << lane) - 1ull;
#pragma unroll
    for (int e = 0; e < NEXP; ++e) {
        bool s = (ei.x == e) | (ei.y == e);
        unsigned long long m = __ballot(s);
        if (lane == 0) wcnt[wv][e] = __popcll(m);
    }
    __syncthreads();
#pragma unroll
    for (int e = 0; e < NEXP; ++e) {
        bool s0 = (ei.x == e);
        bool s  = s0 | (ei.y == e);
        unsigned long long m = __ballot(s);
        int base = offs[e * NCHUNK + blockIdx.x];
        for (int w = 0; w < wv; ++w) base += wcnt[w][e];
        int pos = base + __popcll(m & lmask);
        if (s) {
            tok[e * N_TOK + pos]  = token;
            gate[e * N_TOK + pos] = s0 ? pr.x : pr.y;
        }
    }
}

// ---------------- main: gathered expert FFN, 256x256 tile, BK=64, 8-phase pipeline ----------------
// 512 thr = 8 waves (2Mx4N), per-wave 128x64 output. LDS 128 KiB: A[2][256x64], B[2][256x64] bf16.
// Per K-tile (BK=64): 4 phases, each {ds_read quadrant frags; stage 1 half-tile via
// global_load_lds; s_barrier; lgkmcnt(0); setprio(1); 16 MFMA; setprio(0); s_barrier}.
// Counted vmcnt(6) only at K-tile boundaries (3 half-tiles in flight) - never drains the
// prefetch queue in the main loop (T3+T4). Half-tile schedule (group t = K-tile t):
//   ph1 stages A-m1(t+1) [other buf]; ph2: A-m0(t+2); ph3: B-n0(t+2); ph4: B-n1(t+2) [own buf,
//   regions consumed at ph1/ph1/ph2 resp.]. Every half is issued >=5 phases before first read;
//   boundary vmcnt(6) retires it (checked for all t). Prologue: K0 (4 halves) + K1 (3 halves),
//   vmcnt(6) retires exactly K0. Epilogue peels groups 14 (vmcnt(0)) and 15 (no staging).
__global__ void __launch_bounds__(512, 2) moe_ffn_kernel(
    const ushort_t* __restrict__ xbf, const ushort_t* __restrict__ w1t,
    const float* __restrict__ b1, const float* __restrict__ w2,
    const int* __restrict__ tok, const float* __restrict__ gate,
    const int* __restrict__ cnt, float* __restrict__ out) {
    __shared__ __attribute__((aligned(16))) ushort_t Alds[2][256 * 64];
    __shared__ __attribute__((aligned(16))) ushort_t Blds[2][256 * 64];
    const int e  = blockIdx.z;
    const int ce = cnt[e];
    const int m0 = blockIdx.y * 256;
    if (m0 >= ce) return;
    const int h0 = blockIdx.x * 256;
    const int t    = threadIdx.x;
    const int wv   = t >> 6;
    const int lane = t & 63;
    const int wr   = wv >> 2;      // 0..1 wave row (128 rows each)
    const int wc   = wv & 3;       // 0..3 wave col (64 cols each)
    const int quad = lane >> 4;
    const int ln   = lane & 15;
    const int lr   = lane >> 3;    // 0..7: row within a 1KB staging chunk
    const int lc   = lane & 7;     // k-chunk slot within row
    const int csrc = (lc ^ lr) << 3;   // pre-swizzled global source chunk (elements)

    const int tbase = e * N_TOK;
    // A staging sources (token gather). Rows: m0 + wr*128 + h*64 + wc*16 + j*8 + lr
    const int ab = wr * 128 + wc * 16 + lr;
    const int r00 = m0 + ab,       r01 = m0 + ab + 8;
    const int r10 = m0 + ab + 64,  r11 = m0 + ab + 72;
    const ushort_t* pA00 = xbf + (size_t)tok[tbase + (r00 < ce ? r00 : m0)] * DIM + csrc;
    const ushort_t* pA01 = xbf + (size_t)tok[tbase + (r01 < ce ? r01 : m0)] * DIM + csrc;
    const ushort_t* pA10 = xbf + (size_t)tok[tbase + (r10 < ce ? r10 : m0)] * DIM + csrc;
    const ushort_t* pA11 = xbf + (size_t)tok[tbase + (r11 < ce ? r11 : m0)] * DIM + csrc;
    // B staging sources. Rows (h-dim): wc*64 + h*32 + wr*16 + j*8 + lr
    const int bb = wc * 64 + wr * 16 + lr;
    const ushort_t* pB00 = w1t + ((size_t)e * HID + h0 + bb) * DIM + csrc;
    const ushort_t* pB01 = pB00 + (size_t)8 * DIM;
    const ushort_t* pB10 = pB00 + (size_t)32 * DIM;
    const ushort_t* pB11 = pB00 + (size_t)40 * DIM;
    // LDS staging dest offsets (ushorts). Linear dest; swizzle lives in the source address.
    const int adst = (wr * 128 + wc * 16 + lr) * 64 + lc * 8;
    const int bdst = (wc * 64 + wr * 16 + lr) * 64 + lc * 8;
    // Fragment read offsets (swizzled k-chunk per 16-lane group; conflict-free, measured 0)
    const int koff0 = ((quad)     ^ (ln & 7)) << 3;
    const int koff1 = ((quad + 4) ^ (ln & 7)) << 3;
    const int arow = (wr * 128 + ln) * 64;
    const int brow = (wc * 64  + ln) * 64;

    ushort_t* const A0 = &Alds[0][0]; ushort_t* const A1 = &Alds[1][0];
    ushort_t* const B0 = &Blds[0][0]; ushort_t* const B1 = &Blds[1][0];

    f32x4 acc[8][4];
    const f32x4 vzero = {0.f, 0.f, 0.f, 0.f};
#pragma unroll
    for (int a = 0; a < 8; ++a)
#pragma unroll
        for (int b = 0; b < 4; ++b) acc[a][b] = vzero;
    bf16x8 af[8], bq0[4], bq1[4];

#define STAGE_A(BUF, h, j, koff) gl_lds16(pA##h##j + (koff), (BUF) + adst + (h)*4096 + (j)*512)
#define STAGE_B(BUF, h, j, koff) gl_lds16(pB##h##j + (koff), (BUF) + bdst + (h)*2048 + (j)*512)

#define LDA(BUF, mh) do { \
    _Pragma("unroll") for (int mi = 0; mi < 4; ++mi) { \
        af[mi*2+0] = *(const bf16x8*)&(BUF)[arow + (mh)*4096 + mi*1024 + koff0]; \
        af[mi*2+1] = *(const bf16x8*)&(BUF)[arow + (mh)*4096 + mi*1024 + koff1]; \
    } } while (0)

#define LDB(BUF, nh, BR) do { \
    _Pragma("unroll") for (int ni = 0; ni < 2; ++ni) { \
        (BR)[ni*2+0] = *(const bf16x8*)&(BUF)[brow + (nh)*2048 + ni*1024 + koff0]; \
        (BR)[ni*2+1] = *(const bf16x8*)&(BUF)[brow + (nh)*2048 + ni*1024 + koff1]; \
    } } while (0)

#define MMAQ(mh, nh, BR) do { \
    _Pragma("unroll") for (int ks = 0; ks < 2; ++ks) \
    _Pragma("unroll") for (int mi = 0; mi < 4; ++mi) \
    _Pragma("unroll") for (int ni = 0; ni < 2; ++ni) \
        acc[(mh)*4+mi][(nh)*2+ni] = __builtin_amdgcn_mfma_f32_16x16x32_bf16( \
            af[mi*2+ks], (BR)[ni*2+ks], acc[(mh)*4+mi][(nh)*2+ni], 0, 0, 0); \
    } while (0)

#define PH_MID() \
    __builtin_amdgcn_s_barrier(); \
    asm volatile("s_waitcnt lgkmcnt(0)" ::: "memory"); \
    __builtin_amdgcn_s_setprio(1)
#define PH_END() \
    __builtin_amdgcn_s_setprio(0); \
    __builtin_amdgcn_s_barrier(); \
    asm volatile("" ::: "memory")
#define PH_ENDB() \
    __builtin_amdgcn_s_setprio(0); \
    asm volatile("s_waitcnt vmcnt(6)" ::: "memory"); \
    __builtin_amdgcn_s_barrier(); \
    asm volatile("" ::: "memory")

#define GROUP(AC, BC, AN, BN_, kA1, kN) do { \
    LDA(AC, 0); LDB(BC, 0, bq0); \
    STAGE_A(AN, 1, 0, kA1); STAGE_A(AN, 1, 1, kA1); \
    PH_MID(); MMAQ(0, 0, bq0); PH_END(); \
    LDB(BC, 1, bq1); \
    STAGE_A(AC, 0, 0, kN); STAGE_A(AC, 0, 1, kN); \
    PH_MID(); MMAQ(0, 1, bq1); PH_END(); \
    LDA(AC, 1); \
    STAGE_B(BC, 0, 0, kN); STAGE_B(BC, 0, 1, kN); \
    PH_MID(); MMAQ(1, 1, bq1); PH_END(); \
    STAGE_B(BC, 1, 0, kN); STAGE_B(BC, 1, 1, kN); \
    PH_MID(); MMAQ(1, 0, bq0); PH_ENDB(); \
    } while (0)

    // ---- prologue: K0 full (4 halves) + K1 first 3 halves; vmcnt(6) retires exactly K0 ----
    STAGE_A(A0, 0, 0, 0);  STAGE_A(A0, 0, 1, 0);
    STAGE_A(A0, 1, 0, 0);  STAGE_A(A0, 1, 1, 0);
    STAGE_B(B0, 0, 0, 0);  STAGE_B(B0, 0, 1, 0);
    STAGE_B(B0, 1, 0, 0);  STAGE_B(B0, 1, 1, 0);
    STAGE_A(A1, 0, 0, 64); STAGE_A(A1, 0, 1, 64);
    STAGE_B(B1, 0, 0, 64); STAGE_B(B1, 0, 1, 64);
    STAGE_B(B1, 1, 0, 64); STAGE_B(B1, 1, 1, 64);
    asm volatile("s_waitcnt vmcnt(6)" ::: "memory");
    __builtin_amdgcn_s_barrier();
    asm volatile("" ::: "memory");

    // ---- main loop: groups 0..13 (tiles k = i*128, i*128+64), pointers advance 128/iter ----
#pragma unroll 1
    for (int i = 0; i < 7; ++i) {
        GROUP(A0, B0, A1, B1, 64, 128);
        GROUP(A1, B1, A0, B0, 128, 192);
        pA00 += 128; pA01 += 128; pA10 += 128; pA11 += 128;
        pB00 += 128; pB01 += 128; pB10 += 128; pB11 += 128;
    }

    // ---- peeled group 14 (tile k=896, buf0): only A-m1(15) left to stage; drain at end ----
    LDA(A0, 0); LDB(B0, 0, bq0);
    STAGE_A(A1, 1, 0, 64); STAGE_A(A1, 1, 1, 64);
    PH_MID(); MMAQ(0, 0, bq0); PH_END();
    LDB(B0, 1, bq1);
    PH_MID(); MMAQ(0, 1, bq1); PH_END();
    LDA(A0, 1);
    PH_MID(); MMAQ(1, 1, bq1); PH_END();
    PH_MID(); MMAQ(1, 0, bq0);
    __builtin_amdgcn_s_setprio(0);
    asm volatile("s_waitcnt vmcnt(0)" ::: "memory");
    __builtin_amdgcn_s_barrier();
    asm volatile("" ::: "memory");

    // ---- peeled group 15 (tile k=960, buf1): no staging ----
    LDA(A1, 0); LDB(B1, 0, bq0);
    PH_MID(); MMAQ(0, 0, bq0); PH_END();
    LDB(B1, 1, bq1);
    PH_MID(); MMAQ(0, 1, bq1); PH_END();
    LDA(A1, 1);
    PH_MID(); MMAQ(1, 1, bq1); PH_END();
    PH_MID(); MMAQ(1, 0, bq0);
    __builtin_amdgcn_s_setprio(0);

    // ---- epilogue: relu(acc+b1)*w2, reduce over the wave's 64 h-cols, atomic per row ----
    const float* b1p = b1 + e * HID + h0 + wc * 64;
    const float* w2p = w2 + e * HID + h0 + wc * 64;
#pragma unroll
    for (int a = 0; a < 8; ++a) {
        float part[4] = {0.f, 0.f, 0.f, 0.f};
#pragma unroll
        for (int b = 0; b < 4; ++b) {
            const int hh = (b >> 1) * 32 + (b & 1) * 16 + ln;
            const float bbv = b1p[hh];
            const float ww  = w2p[hh];
#pragma unroll
            for (int rg = 0; rg < 4; ++rg) {
                float v = acc[a][b][rg] + bbv;
                v = v > 0.f ? v : 0.f;
                part[rg] += v * ww;
            }
        }
#pragma unroll
        for (int rg = 0; rg < 4; ++rg) {
            float v = part[rg];
            v += __shfl_xor(v, 1, 64);
            v += __shfl_xor(v, 2, 64);
            v += __shfl_xor(v, 4, 64);
            v += __shfl_xor(v, 8, 64);
            part[rg] = v;
        }
        if (ln == 0) {
            const int rbase = m0 + wr * 128 + (a >> 2) * 64 + (a & 3) * 16 + quad * 4;
#pragma unroll
            for (int rg = 0; rg < 4; ++rg) {
                const int r = rbase + rg;
                if (r < ce) {
                    atomicAdd(&out[tok[tbase + r]], gate[tbase + r] * part[rg]);
                }
            }
        }
    }
#undef STAGE_A
#undef STAGE_B
#undef LDA
#undef LDB
#undef MMAQ
#undef PH_MID
#undef PH_END
#undef PH_ENDB
#undef GROUP
}

extern "C" void kernel_launch(void* const* d_in, const int* in_sizes, int n_in,
                              void* d_out, int out_size, void* d_ws, size_t ws_size,
                              hipStream_t stream) {
    (void)in_sizes; (void)n_in; (void)out_size; (void)ws_size;
    const float* x  = (const float*)d_in[0];
    // d_in[1]=Wr, d_in[2]=br are dead in the reference
    const float* Wn = (const float*)d_in[3];
    const float* bn = (const float*)d_in[4];
    const float* W1 = (const float*)d_in[5];
    const float* b1 = (const float*)d_in[6];
    const float* W2 = (const float*)d_in[7];
    const float* b2 = (const float*)d_in[8];
    float* out = (float*)d_out;

    char* ws = (char*)d_ws;
    ushort_t* xbf = (ushort_t*)ws;                                     // 32 MB
    ushort_t* w1t = (ushort_t*)(ws + (size_t)32 * 1024 * 1024);        // 128 MB
    char* p2 = ws + (size_t)160 * 1024 * 1024;
    size_t off = 0;
    int*    tok    = (int*)(p2 + off);    off += (size_t)NEXP * N_TOK * 4;   // 1 MB
    float*  gate   = (float*)(p2 + off);  off += (size_t)NEXP * N_TOK * 4;   // 1 MB
    int*    cnt    = (int*)(p2 + off);    off += 256;
    int2*   eidx   = (int2*)(p2 + off);   off += (size_t)N_TOK * 8;          // 128 KB
    float2* probs  = (float2*)(p2 + off); off += (size_t)N_TOK * 8;          // 128 KB
    int*    counts = (int*)(p2 + off);    off += NEXP * NCHUNK * 4;          // 4 KB
    int*    offs   = (int*)(p2 + off);    off += NEXP * NCHUNK * 4;          // 4 KB

    // fused transpose (z<16) + router (z>=16): overlaps W1's 384MB HBM stream with
    // the router's L2-resident Wn matvecs; also makes the prep cost visible in top-5.
    prep_kernel<<<dim3(64, 16, 20), 256, 0, stream>>>(x, Wn, bn, b2, W1,
                                                      xbf, w1t, eidx, probs, out);
    hist_kernel<<<NCHUNK, 256, 0, stream>>>(eidx, counts);
    scan_kernel<<<1, 1024, 0, stream>>>(counts, offs, cnt);
    scatter_kernel<<<NCHUNK, 256, 0, stream>>>(eidx, probs, offs, tok, gate);
    moe_ffn_kernel<<<dim3(HID / 256, 32, NEXP), 512, 0, stream>>>(xbf, w1t, b1, W2, tok,
                                                                  gate, cnt, out);
}

// Round 4
// 870.541 us; speedup vs baseline: 1.1300x; 1.1300x over previous
//
#include <hip/hip_runtime.h>
#include <stdint.h>

#define N_TOK 16384
#define DIM   1024
#define NEXP  16
#define HID   4096

typedef unsigned short ushort_t;
typedef __bf16 bf16x8 __attribute__((ext_vector_type(8)));
typedef float  f32x4  __attribute__((ext_vector_type(4)));
typedef ushort_t u16x8 __attribute__((ext_vector_type(8)));

// round-to-nearest-even fp32 -> bf16
__device__ __forceinline__ ushort_t f2bf(float f) {
    union { float f; unsigned int u; } v; v.f = f;
    unsigned int r = v.u + 0x7fffu + ((v.u >> 16) & 1u);
    return (ushort_t)(r >> 16);
}

__device__ __forceinline__ void gl_lds16(const void* g, void* l) {
    __builtin_amdgcn_global_load_lds(
        (const __attribute__((address_space(1))) void*)g,
        (__attribute__((address_space(3))) void*)l, 16, 0, 0);
}

// ---------------- transpose+cast W1: [E][D][H] fp32 -> [E][H][D] bf16 ----------------
// 64d x 256h per block: per d-row the block reads a CONTIGUOUS 1KB burst
// (16 hs-lanes x 4 ii-subtiles x 16B), vs the old 4 disjoint 256B bursts.
// Inner core per 64x64 subtile: proven float4 read -> 4x4 reg micro-transpose ->
// LDS (stride 72 keeps 16B alignment) -> ushort8 stores (128B per h-row).
#define TS 72
__global__ void __launch_bounds__(256) transpose_w1_kernel(const float* __restrict__ W1,
                                                           ushort_t* __restrict__ w1t) {
    __shared__ ushort_t tileT[64 * TS];
    const int e  = blockIdx.z;
    const int h0 = blockIdx.x * 256;
    const int d0 = blockIdx.y * 64;
    const int t  = threadIdx.x;
    const int hs = t & 15;   // h-group of 4 floats
    const int dg = t >> 4;   // d-group of 4 rows
    const float* src = W1 + (size_t)e * DIM * HID;
    float4 rows[4][4];   // [ii][i] : ii = 64h-subtile, i = d-row within group
#pragma unroll
    for (int i = 0; i < 4; ++i) {
        const float* rp = src + (size_t)(d0 + dg * 4 + i) * HID + h0 + hs * 4;
#pragma unroll
        for (int ii = 0; ii < 4; ++ii)
            rows[ii][i] = *(const float4*)(rp + ii * 64);
    }
    ushort_t* dst = w1t + (size_t)e * HID * DIM;
#pragma unroll
    for (int ii = 0; ii < 4; ++ii) {
        if (ii) __syncthreads();   // LDS reuse across subtiles
#pragma unroll
        for (int j = 0; j < 4; ++j) {
            float v0 = (&rows[ii][0].x)[j], v1 = (&rows[ii][1].x)[j];
            float v2 = (&rows[ii][2].x)[j], v3 = (&rows[ii][3].x)[j];
            ushort4 col; col.x = f2bf(v0); col.y = f2bf(v1); col.z = f2bf(v2); col.w = f2bf(v3);
            *(ushort4*)&tileT[(hs * 4 + j) * TS + dg * 4] = col;
        }
        __syncthreads();
#pragma unroll
        for (int p = 0; p < 2; ++p) {
            int r = p * 32 + (t >> 3);
            int c = t & 7;
            u16x8 fr = *(const u16x8*)&tileT[r * TS + c * 8];
            *(u16x8*)(dst + (size_t)(h0 + ii * 64 + r) * DIM + d0 + c * 8) = fr;
        }
    }
}

// ---------------- router: logits -> top2 -> per-token (eidx, probs); also emit xbf ----------------
// wave per token; NO atomics.
__global__ void __launch_bounds__(256) router_logits_kernel(
    const float* __restrict__ x, const float* __restrict__ Wn,
    const float* __restrict__ bn, const float* __restrict__ b2,
    ushort_t* __restrict__ xbf, int2* __restrict__ eidx,
    float2* __restrict__ probs, float* __restrict__ out) {
    int wave  = threadIdx.x >> 6;
    int lane  = threadIdx.x & 63;
    int token = blockIdx.x * 4 + wave;
    const float* xr = x + (size_t)token * DIM;
    float acc[NEXP];
#pragma unroll
    for (int e = 0; e < NEXP; ++e) acc[e] = 0.f;
    ushort_t xl[16];
#pragma unroll
    for (int i = 0; i < 16; ++i) {
        int d = lane + i * 64;
        float xv = xr[d];
        xl[i] = f2bf(xv);
        const float4* wr = (const float4*)(Wn + d * NEXP);
        float4 w0 = wr[0], w1 = wr[1], w2 = wr[2], w3 = wr[3];
        acc[0]  += xv * w0.x; acc[1]  += xv * w0.y; acc[2]  += xv * w0.z; acc[3]  += xv * w0.w;
        acc[4]  += xv * w1.x; acc[5]  += xv * w1.y; acc[6]  += xv * w1.z; acc[7]  += xv * w1.w;
        acc[8]  += xv * w2.x; acc[9]  += xv * w2.y; acc[10] += xv * w2.z; acc[11] += xv * w2.w;
        acc[12] += xv * w3.x; acc[13] += xv * w3.y; acc[14] += xv * w3.z; acc[15] += xv * w3.w;
    }
    ushort_t* xbr = xbf + (size_t)token * DIM;
#pragma unroll
    for (int i = 0; i < 16; ++i) xbr[lane + i * 64] = xl[i];
#pragma unroll
    for (int e = 0; e < NEXP; ++e) {
        float v = acc[e];
#pragma unroll
        for (int off = 32; off > 0; off >>= 1) v += __shfl_xor(v, off, 64);
        acc[e] = v + bn[e];
    }
    if (lane == 0) {
        float m0 = -1e30f; int i0 = 0;
        for (int e = 0; e < NEXP; ++e) if (acc[e] > m0) { m0 = acc[e]; i0 = e; }
        float m1 = -1e30f; int i1 = 0;
        for (int e = 0; e < NEXP; ++e) if (e != i0 && acc[e] > m1) { m1 = acc[e]; i1 = e; }
        float tq = expf(m1 - m0);          // m1 <= m0, safe
        float p0 = 1.f / (1.f + tq);
        float p1 = 1.f - p0;
        eidx[token]  = make_int2(i0, i1);
        probs[token] = make_float2(p0, p1);
        out[token]   = p0 * b2[i0] + p1 * b2[i1];
    }
}

// ---------------- bucket build: hist -> scan -> scatter (all parallel, no global atomics) --------
#define NCHUNK 64
#define CHUNK  (N_TOK / NCHUNK)   // 256 tokens per chunk

__global__ void __launch_bounds__(256) hist_kernel(const int2* __restrict__ eidx,
                                                   int* __restrict__ counts) {
    __shared__ int h[NEXP];
    const int t = threadIdx.x;
    if (t < NEXP) h[t] = 0;
    __syncthreads();
    int token = blockIdx.x * CHUNK + t;
    int2 ei = eidx[token];
    atomicAdd(&h[ei.x], 1);
    atomicAdd(&h[ei.y], 1);
    __syncthreads();
    if (t < NEXP) counts[t * NCHUNK + blockIdx.x] = h[t];
}

// 1 block, 1024 threads = 16 waves; wave w = expert w, lane = chunk.
__global__ void __launch_bounds__(1024) scan_kernel(const int* __restrict__ counts,
                                                    int* __restrict__ offs,
                                                    int* __restrict__ cnt) {
    const int w    = threadIdx.x >> 6;
    const int lane = threadIdx.x & 63;
    int v = counts[w * NCHUNK + lane];
    int orig = v;
#pragma unroll
    for (int off = 1; off < 64; off <<= 1) {
        int up = __shfl_up(v, off, 64);
        if (lane >= off) v += up;
    }
    offs[w * NCHUNK + lane] = v - orig;   // exclusive prefix within expert
    if (lane == 63) cnt[w] = v;
}

__global__ void __launch_bounds__(256) scatter_kernel(
    const int2* __restrict__ eidx, const float2* __restrict__ probs,
    const int* __restrict__ offs, int* __restrict__ tok, float* __restrict__ gate) {
    __shared__ int wcnt[4][NEXP];
    const int t = threadIdx.x;
    const int wv = t >> 6, lane = t & 63;
    const int token = blockIdx.x * CHUNK + t;
    int2  ei = eidx[token];
    float2 pr = probs[token];
    unsigned long long lmask = (1ull << lane) - 1ull;
#pragma unroll
    for (int e = 0; e < NEXP; ++e) {
        bool s = (ei.x == e) | (ei.y == e);
        unsigned long long m = __ballot(s);
        if (lane == 0) wcnt[wv][e] = __popcll(m);
    }
    __syncthreads();
#pragma unroll
    for (int e = 0; e < NEXP; ++e) {
        bool s0 = (ei.x == e);
        bool s  = s0 | (ei.y == e);
        unsigned long long m = __ballot(s);
        int base = offs[e * NCHUNK + blockIdx.x];
        for (int w = 0; w < wv; ++w) base += wcnt[w][e];
        int pos = base + __popcll(m & lmask);
        if (s) {
            tok[e * N_TOK + pos]  = token;
            gate[e * N_TOK + pos] = s0 ? pr.x : pr.y;
        }
    }
}

// ---------------- main: gathered expert FFN, bf16 MFMA 128x128xK tile ----------------
// VERIFIED round-0 structure (753 TF): 32KB LDS -> ~3.5 blocks/CU, implicit wave-level
// overlap (m114) covers the vmcnt(0)+barrier drain. Split into 2 dispatches (eoff)
// so aux kernels >~190us become visible in top-5.
// grid: (HID/128, 64, 8), block 256
__global__ void __launch_bounds__(256, 2) moe_ffn_kernel(
    const ushort_t* __restrict__ xbf, const ushort_t* __restrict__ w1t,
    const float* __restrict__ b1, const float* __restrict__ w2,
    const int* __restrict__ tok, const float* __restrict__ gate,
    const int* __restrict__ cnt, float* __restrict__ out, int eoff) {
    __shared__ ushort_t Alds[128 * 64];
    __shared__ ushort_t Blds[128 * 64];
    const int e  = blockIdx.z + eoff;
    const int ce = cnt[e];
    const int m0 = blockIdx.y * 128;
    if (m0 >= ce) return;
    const int h0 = blockIdx.x * 128;
    const int t    = threadIdx.x;
    const int wv   = t >> 6;
    const int lane = t & 63;
    const int quad = lane >> 4;
    const int ln   = lane & 15;
    const int wm   = (wv >> 1) * 64;   // wave M offset in tile
    const int wn   = (wv & 1) * 64;    // wave N offset in tile

    // Token ids for the A rows this thread stages (clamped into bucket; m0 < ce)
    int tkid[4];
#pragma unroll
    for (int i = 0; i < 4; ++i) {
        int f = i * 256 + t;
        int r = f >> 3;
        int rr = (m0 + r < ce) ? (m0 + r) : m0;
        tkid[i] = tok[e * N_TOK + rr];
    }

    f32x4 acc[4][4];
    const f32x4 zero = {0.f, 0.f, 0.f, 0.f};
#pragma unroll
    for (int mi = 0; mi < 4; ++mi)
#pragma unroll
        for (int ni = 0; ni < 4; ++ni) acc[mi][ni] = zero;

    for (int k0 = 0; k0 < DIM; k0 += 64) {
        // Stage A(128x64) and B(128x64, rows=h, cols=d) with XOR-swizzled 16B chunks.
        // LDS slot (r*8 + c) holds global k-chunk (c ^ (r&7)) of row r.
#pragma unroll
        for (int i = 0; i < 4; ++i) {
            int f = i * 256 + t;
            int r = f >> 3, c = f & 7;
            int cs = (c ^ (r & 7)) << 3;
            const ushort_t* ga = xbf + (size_t)tkid[i] * DIM + k0 + cs;
            gl_lds16(ga, &Alds[f * 8]);
            const ushort_t* gb = w1t + ((size_t)e * HID + h0 + r) * DIM + k0 + cs;
            gl_lds16(gb, &Blds[f * 8]);
        }
        __syncthreads();
#pragma unroll
        for (int ks = 0; ks < 2; ++ks) {
            int q = ks * 4 + quad;               // k-chunk index within row
            int csw = (q ^ (ln & 7)) << 3;       // swizzled element offset
            bf16x8 af[4], bfr[4];
#pragma unroll
            for (int mi = 0; mi < 4; ++mi)
                af[mi] = *(const bf16x8*)&Alds[(wm + mi * 16 + ln) * 64 + csw];
#pragma unroll
            for (int ni = 0; ni < 4; ++ni)
                bfr[ni] = *(const bf16x8*)&Blds[(wn + ni * 16 + ln) * 64 + csw];
#pragma unroll
            for (int mi = 0; mi < 4; ++mi)
#pragma unroll
                for (int ni = 0; ni < 4; ++ni)
                    acc[mi][ni] = __builtin_amdgcn_mfma_f32_16x16x32_bf16(
                        af[mi], bfr[ni], acc[mi][ni], 0, 0, 0);
        }
        __syncthreads();
    }

    // Epilogue: relu(acc + b1) * w2, reduce over the 64 h-columns this wave owns,
    // then atomicAdd gate*partial into out[token].
#pragma unroll
    for (int mi = 0; mi < 4; ++mi) {
        float part[4] = {0.f, 0.f, 0.f, 0.f};
#pragma unroll
        for (int ni = 0; ni < 4; ++ni) {
            int h = h0 + wn + ni * 16 + ln;
            float bb = b1[e * HID + h];
            float ww = w2[e * HID + h];
#pragma unroll
            for (int rg = 0; rg < 4; ++rg) {
                float v = acc[mi][ni][rg] + bb;
                v = v > 0.f ? v : 0.f;
                part[rg] += v * ww;
            }
        }
#pragma unroll
        for (int rg = 0; rg < 4; ++rg) {
            float v = part[rg];
            v += __shfl_xor(v, 1, 64);
            v += __shfl_xor(v, 2, 64);
            v += __shfl_xor(v, 4, 64);
            v += __shfl_xor(v, 8, 64);
            part[rg] = v;
        }
        if (ln == 0) {
#pragma unroll
            for (int rg = 0; rg < 4; ++rg) {
                int r = m0 + wm + mi * 16 + quad * 4 + rg;
                if (r < ce) {
                    int tk  = tok[e * N_TOK + r];
                    float g = gate[e * N_TOK + r];
                    atomicAdd(&out[tk], g * part[rg]);
                }
            }
        }
    }
}

extern "C" void kernel_launch(void* const* d_in, const int* in_sizes, int n_in,
                              void* d_out, int out_size, void* d_ws, size_t ws_size,
                              hipStream_t stream) {
    (void)in_sizes; (void)n_in; (void)out_size; (void)ws_size;
    const float* x  = (const float*)d_in[0];
    // d_in[1]=Wr, d_in[2]=br are dead in the reference
    const float* Wn = (const float*)d_in[3];
    const float* bn = (const float*)d_in[4];
    const float* W1 = (const float*)d_in[5];
    const float* b1 = (const float*)d_in[6];
    const float* W2 = (const float*)d_in[7];
    const float* b2 = (const float*)d_in[8];
    float* out = (float*)d_out;

    char* ws = (char*)d_ws;
    ushort_t* xbf = (ushort_t*)ws;                                     // 32 MB
    ushort_t* w1t = (ushort_t*)(ws + (size_t)32 * 1024 * 1024);        // 128 MB
    char* p2 = ws + (size_t)160 * 1024 * 1024;
    size_t off = 0;
    int*    tok    = (int*)(p2 + off);    off += (size_t)NEXP * N_TOK * 4;   // 1 MB
    float*  gate   = (float*)(p2 + off);  off += (size_t)NEXP * N_TOK * 4;   // 1 MB
    int*    cnt    = (int*)(p2 + off);    off += 256;
    int2*   eidx   = (int2*)(p2 + off);   off += (size_t)N_TOK * 8;          // 128 KB
    float2* probs  = (float2*)(p2 + off); off += (size_t)N_TOK * 8;          // 128 KB
    int*    counts = (int*)(p2 + off);    off += NEXP * NCHUNK * 4;          // 4 KB
    int*    offs   = (int*)(p2 + off);    off += NEXP * NCHUNK * 4;          // 4 KB

    router_logits_kernel<<<N_TOK / 4, 256, 0, stream>>>(x, Wn, bn, b2, xbf, eidx, probs, out);
    hist_kernel<<<NCHUNK, 256, 0, stream>>>(eidx, counts);
    scan_kernel<<<1, 1024, 0, stream>>>(counts, offs, cnt);
    scatter_kernel<<<NCHUNK, 256, 0, stream>>>(eidx, probs, offs, tok, gate);
    // transpose right before the FFN so w1t is freshest in L3
    transpose_w1_kernel<<<dim3(HID / 256, DIM / 64, NEXP), 256, 0, stream>>>(W1, w1t);
    // FFN split into 2 dispatches (experts 0-7, 8-15): same total work, and frees
    // top-5 slots so any aux kernel >~190us becomes visible with counters.
    moe_ffn_kernel<<<dim3(HID / 128, 64, NEXP / 2), 256, 0, stream>>>(xbf, w1t, b1, W2, tok,
                                                                      gate, cnt, out, 0);
    moe_ffn_kernel<<<dim3(HID / 128, 64, NEXP / 2), 256, 0, stream>>>(xbf, w1t, b1, W2, tok,
                                                                      gate, cnt, out, 8);
}